// Round 8
// baseline (159.905 us; speedup 1.0000x reference)
//
#include <hip/hip_runtime.h>
#include <math.h>

// eDCC loss: reference reads only projs[0,127,:,:] and projs[0,29,:,:].
// P_i[l] = sum_s projs[127,l,s]*w[s], P_j[l] = sum_s projs[29,l,s]*w[s],
// w[s] = exp(sigma * s_grid[s] * SPACING), sigma = 0.013*tan(pi*98/128),
// s_grid[s] = (s-127.5)*SPACING.  out = sum_l (2/128)*|Pi-Pj|/(Pi+Pj).
//
// R3 post-mortem: dur_us floor (~155 us) is harness re-poison traffic
// (512 MB fill at 86% HBM peak). Controllable share ~5-7 us. This round:
// single dispatch (no memset node) via ws partials + flag handshake;
// 64 blocks so the 2 MB read spreads over 64 CUs (~24 GB/s/CU each).
// R4-R7: infra failures (acquisition timeout), same kernel resubmitted.

#define L_ROWS   1024
#define S_LEN    256
#define I_ROW    127
#define J_ROW    29
#define THREADS  256             // 4 waves/block
#define BLOCKS   64              // 256 waves total, 4 rows each
#define MAGIC    0x13579BDFu     // != 0xAAAAAAAA poison, != 0

__global__ __launch_bounds__(THREADS) void edcc_kernel(const float* __restrict__ projs,
                                                       float* __restrict__ out,
                                                       float* __restrict__ ws_part,
                                                       unsigned* __restrict__ ws_flag) {
    const int wid  = threadIdx.x >> 6;                 // wave in block [0,4)
    const int lane = threadIdx.x & 63;
    const int gw   = blockIdx.x * (THREADS / 64) + wid; // global wave [0,256)

    // Per-lane Laplace weights (double constants, cast late; |arg| <= 34.6).
    const double sigma = 0.013 * tan((98.0 * (6.283185307179586 / 128.0)) * 0.5);
    float w[4];
#pragma unroll
    for (int c = 0; c < 4; ++c) {
        const double s_k = ((double)(lane * 4 + c) - 127.5) * 4.7952;
        w[c] = expf((float)(sigma * s_k * 4.7952));
    }

    float term_sum = 0.0f;
#pragma unroll
    for (int r = 0; r < 4; ++r) {
        const int l = gw + 256 * r;                    // 4 rows per wave
        const float* rowi = projs + ((size_t)(I_ROW * L_ROWS + l)) * S_LEN;
        const float* rowj = projs + ((size_t)(J_ROW * L_ROWS + l)) * S_LEN;
        const float4 vi = *reinterpret_cast<const float4*>(rowi + lane * 4);
        const float4 vj = *reinterpret_cast<const float4*>(rowj + lane * 4);

        float pi = fmaf(vi.x, w[0], fmaf(vi.y, w[1], fmaf(vi.z, w[2], vi.w * w[3])));
        float pj = fmaf(vj.x, w[0], fmaf(vj.y, w[1], fmaf(vj.z, w[2], vj.w * w[3])));

#pragma unroll
        for (int off = 32; off > 0; off >>= 1) {
            pi += __shfl_xor(pi, off);
            pj += __shfl_xor(pj, off);
        }
        const float den = pi + pj;
        if (den != 0.0f)
            term_sum += (2.0f / 128.0f) * fabsf(pi - pj) / den;
    }

    // Block reduce (4 waves) in LDS.
    __shared__ float lds[THREADS / 64];
    if (lane == 0) lds[wid] = term_sum;
    __syncthreads();

    if (wid == 0) {
        if (lane == 0) {
            float p = lds[0] + lds[1] + lds[2] + lds[3];
            // Publish partial then flag, both at device scope (atomics hit the
            // coherent point; fence orders them across XCD L2s).
            atomicExch(&ws_part[blockIdx.x], p);
            __threadfence();
            atomicExch(&ws_flag[blockIdx.x], MAGIC);
        }
        // Block 0 wave 0: gather all 64 partials once flags are up.
        if (blockIdx.x == 0) {
            while (atomicAdd(&ws_flag[lane], 0u) != MAGIC) { /* spin */ }
            __threadfence();
            float v = atomicAdd(&ws_part[lane], 0.0f);     // coherent read
#pragma unroll
            for (int off = 32; off > 0; off >>= 1) v += __shfl_xor(v, off);
            if (lane == 0) out[0] = v;                     // full overwrite, no init needed
        }
    }
}

extern "C" void kernel_launch(void* const* d_in, const int* in_sizes, int n_in,
                              void* d_out, int out_size, void* d_ws, size_t ws_size,
                              hipStream_t stream) {
    const float* projs = (const float*)d_in[0];
    float* out = (float*)d_out;
    float* ws_part = (float*)d_ws;                   // 64 floats
    unsigned* ws_flag = (unsigned*)d_ws + BLOCKS;    // 64 uints (bytes 256..511)

    edcc_kernel<<<BLOCKS, THREADS, 0, stream>>>(projs, out, ws_part, ws_flag);
}